// Round 11
// baseline (562.475 us; speedup 1.0000x reference)
//
#include <hip/hip_runtime.h>

#define B_ 64
#define T_ 256
#define DIN_ 1024
#define DOUT_ 1024

typedef int v4i  __attribute__((ext_vector_type(4)));
typedef int v16i __attribute__((ext_vector_type(16)));

#define PRE_BYTES 134217728ULL   // 256*1024*64*8
#define XS_BYTES  100663296ULL   // 6*256*32*2*1024
#define WSL_BYTES 6291456ULL     // 6*32*32*1024
#define SPM_BYTES 2097152ULL     // 256*1024*8

// -----------------------------------------------------------------------------
// Split x into 6 signed-i8 slices, fixed scale 2^3, MFMA A-frag chunk order:
// chunk(s,t,kt,mt) = 1KB, byte = lane*16+j, lane = kh*32+m,
// element = x[b=mt*32+m][t][kt*32+kh*16+j]. All split steps exact in fp32.
// -----------------------------------------------------------------------------
__global__ __launch_bounds__(256) void snn_split_x(
    const float* __restrict__ x, char* __restrict__ xs)
{
    const int W    = blockIdx.x * 4 + (threadIdx.x >> 6);   // 0..16383
    const int lane = threadIdx.x & 63;
    const int mt = W & 1, kt = (W >> 1) & 31, t0 = W >> 6;
    const int m = lane & 31, kh = lane >> 5;
    const int b = mt * 32 + m;

    const float* src = x + ((size_t)b * T_ + t0) * DIN_ + kt * 32 + kh * 16;
    float f[16];
    *(float4*)(f)      = *(const float4*)(src);
    *(float4*)(f + 4)  = *(const float4*)(src + 4);
    *(float4*)(f + 8)  = *(const float4*)(src + 8);
    *(float4*)(f + 12) = *(const float4*)(src + 12);

    unsigned pk[6][4];
#pragma unroll
    for (int s = 0; s < 6; ++s)
        pk[s][0] = pk[s][1] = pk[s][2] = pk[s][3] = 0u;
#pragma unroll
    for (int j = 0; j < 16; ++j) {
        float v = f[j] * 0.125f;                 // / 2^3 (exact)
#pragma unroll
        for (int s = 0; s < 6; ++s) {
            const float ml = (s == 0) ? 64.f : 128.f;
            const float sv = __builtin_rintf(v * ml);
            v = v * ml - sv;                     // exact residual
            const int iv = (int)sv;
            pk[s][j >> 2] |= ((unsigned)iv & 0xffu) << ((j & 3) * 8);
        }
    }
#pragma unroll
    for (int s = 0; s < 6; ++s) {
        char* dst = xs + (size_t)(((s * 256 + t0) * 32 + kt) * 2 + mt) * 1024
                       + lane * 16;
        *(uint4*)dst = make_uint4(pk[s][0], pk[s][1], pk[s][2], pk[s][3]);
    }
}

// -----------------------------------------------------------------------------
// Split W into 6 i8 slices, fixed scale 2^-2, B-frag chunk order:
// chunk(s,ot,kt) = 1KB, element = W[o=ot*32+n][kt*32+kh*16+j].
// -----------------------------------------------------------------------------
__global__ __launch_bounds__(256) void snn_split_w(
    const float* __restrict__ Wt, char* __restrict__ wsl)
{
    const int W    = blockIdx.x * 4 + (threadIdx.x >> 6);   // 0..1023
    const int lane = threadIdx.x & 63;
    const int kt = W & 31, ot = W >> 5;
    const int n = lane & 31, kh = lane >> 5;
    const int o = ot * 32 + n;

    const float* src = Wt + (size_t)o * DIN_ + kt * 32 + kh * 16;
    float f[16];
    *(float4*)(f)      = *(const float4*)(src);
    *(float4*)(f + 4)  = *(const float4*)(src + 4);
    *(float4*)(f + 8)  = *(const float4*)(src + 8);
    *(float4*)(f + 12) = *(const float4*)(src + 12);

    unsigned pk[6][4];
#pragma unroll
    for (int s = 0; s < 6; ++s)
        pk[s][0] = pk[s][1] = pk[s][2] = pk[s][3] = 0u;
#pragma unroll
    for (int j = 0; j < 16; ++j) {
        float v = f[j] * 4.0f;                   // / 2^-2 (exact)
#pragma unroll
        for (int s = 0; s < 6; ++s) {
            const float ml = (s == 0) ? 64.f : 128.f;
            const float sv = __builtin_rintf(v * ml);
            v = v * ml - sv;
            const int iv = (int)sv;
            pk[s][j >> 2] |= ((unsigned)iv & 0xffu) << ((j & 3) * 8);
        }
    }
#pragma unroll
    for (int s = 0; s < 6; ++s) {
        char* dst = wsl + (size_t)((s * 32 + ot) * 32 + kt) * 1024 + lane * 16;
        *(uint4*)dst = make_uint4(pk[s][0], pk[s][1], pk[s][2], pk[s][3]);
    }
}

// -----------------------------------------------------------------------------
// GEMM via i8 MFMA — BARRIER-FREE / LDS-FREE. Each wave reads its own a[6]/b[6]
// fragments direct from global (coalesced 1KB chunks; B is L2-resident per
// XCD via blockIdx=t0*16+oB; A pairs hit L1, rest L3). Register double-buffer
// via 2x-unrolled kt loop. MFMA order a-major: consecutive instrs never hit
// the same acc chain. i32 accumulation is order-independent -> bit-exact.
// -----------------------------------------------------------------------------
#define LOAD_SET(aa, bb, ktv)                                              \
    {                                                                      \
        _Pragma("unroll")                                                  \
        for (int s = 0; s < 6; ++s) {                                      \
            aa[s] = *(const v4i*)(asrc[s] + (size_t)(ktv) * 2048);         \
            bb[s] = *(const v4i*)(bsrc[s] + (size_t)(ktv) * 1024);         \
        }                                                                  \
    }

#define DO_MFMA(aa, bb)                                                    \
    {                                                                      \
        _Pragma("unroll")                                                  \
        for (int i = 0; i < 6; ++i) {                                      \
            _Pragma("unroll")                                              \
            for (int j = 0; j < 6 - i; ++j)                                \
                acc[i + j] = __builtin_amdgcn_mfma_i32_32x32x32_i8(        \
                    aa[i], bb[j], acc[i + j], 0, 0, 0);                    \
        }                                                                  \
    }

__global__ __launch_bounds__(256, 2) void snn_gemm_i8(
    const char* __restrict__ xs, const char* __restrict__ wsl,
    const float* __restrict__ bias, double* __restrict__ pre)
{
    const int t0 = blockIdx.x >> 4;
    const int oB = blockIdx.x & 15;
    const int tid = threadIdx.x;
    const int w = tid >> 6, lane = tid & 63;
    const int wm = w >> 1, wo = w & 1;

    v16i zero;
#pragma unroll
    for (int r = 0; r < 16; ++r) zero[r] = 0;
    v16i acc[6];
#pragma unroll
    for (int g = 0; g < 6; ++g) acc[g] = zero;

    const char* asrc[6];   // kt stride 2048
    const char* bsrc[6];   // kt stride 1024
#pragma unroll
    for (int s = 0; s < 6; ++s) {
        asrc[s] = xs + (size_t)(((s * 256 + t0) * 32) * 2 + wm) * 1024
                     + lane * 16;
        bsrc[s] = wsl + (size_t)((s * 32 + oB * 2 + wo) * 32) * 1024
                      + lane * 16;
    }

    v4i aA[6], bA[6], aB[6], bB[6];
    LOAD_SET(aA, bA, 0);
    for (int kt = 0; kt < 32; kt += 2) {
        LOAD_SET(aB, bB, kt + 1);
        DO_MFMA(aA, bA);
        if (kt + 2 < 32) LOAD_SET(aA, bA, kt + 2);
        DO_MFMA(aB, bB);
    }

    // epilogue: D layout col=lane&31 (o), row=(r&3)+8*(r>>2)+4*(lane>>5) (b)
    const int n = lane & 31, lh = lane >> 5;
    const int o = oB * 64 + wo * 32 + n;
    const double bv = (double)bias[o];
    double* dst = pre + ((size_t)t0 * DOUT_ + o) * 64 + wm * 32;
#pragma unroll
    for (int r = 0; r < 16; ++r) {
        const int row = (r & 3) + 8 * (r >> 2) + 4 * lh;
        double v = (double)acc[5][r];
        v = v * 0.0078125 + (double)acc[4][r];
        v = v * 0.0078125 + (double)acc[3][r];
        v = v * 0.0078125 + (double)acc[2][r];
        v = v * 0.0078125 + (double)acc[1][r];
        v = v * 0.0078125 + (double)acc[0][r];
        dst[row] = v * 0x1p-11 + bv;             // 2^{3-2-12}
    }
}

// -----------------------------------------------------------------------------
// Fallback GEMM (round-8 proven fp64-VALU path), used when ws is small.
// -----------------------------------------------------------------------------
__global__ __launch_bounds__(256, 2) void snn_gemm_fb(
    const float* __restrict__ x, const float* __restrict__ W,
    const float* __restrict__ bias, double* __restrict__ pre)
{
    __shared__ float smem[2][8 * 72 + 8 * 256];
    const int t0 = blockIdx.x & 255;
    const int o0 = blockIdx.x >> 8;
    const int tid = threadIdx.x;
    const int to = tid & 31;
    const int tb = tid >> 5;

    double acc[8][8];
#pragma unroll
    for (int i = 0; i < 8; ++i)
#pragma unroll
        for (int j = 0; j < 8; ++j) acc[i][j] = 0.0;

    const int arow = tid >> 2;
    const int ak2  = (tid & 3) * 2;
    const float* xg = x + (size_t)(t0 + 256 * arow) * DIN_ + ak2;
    const float* wg = W + (size_t)(o0 * 256 + tid) * DIN_;

    float2 f2  = *(const float2*)(xg);
    float4 bq0 = *(const float4*)(wg);
    float4 bq1 = *(const float4*)(wg + 4);

    for (int kc = 0; kc < DIN_ / 8; ++kc) {
        float* base = smem[kc & 1];
        float (*AsF)[72]  = (float(*)[72])base;
        float (*BsF)[256] = (float(*)[256])(base + 8 * 72);
        AsF[ak2 + 0][arow] = f2.x;
        AsF[ak2 + 1][arow] = f2.y;
        BsF[0][tid] = bq0.x;  BsF[1][tid] = bq0.y;
        BsF[2][tid] = bq0.z;  BsF[3][tid] = bq0.w;
        BsF[4][tid] = bq1.x;  BsF[5][tid] = bq1.y;
        BsF[6][tid] = bq1.z;  BsF[7][tid] = bq1.w;
        __syncthreads();
        if (kc + 1 < DIN_ / 8) {
            f2  = *(const float2*)(xg + (kc + 1) * 8);
            bq0 = *(const float4*)(wg + (kc + 1) * 8);
            bq1 = *(const float4*)(wg + (kc + 1) * 8 + 4);
        }
#pragma unroll
        for (int k = 0; k < 8; ++k) {
            const float4 af0 = *(const float4*)&AsF[k][tb * 8];
            const float4 af1 = *(const float4*)&AsF[k][tb * 8 + 4];
            const float4 bf0 = *(const float4*)&BsF[k][to * 4];
            const float4 bf1 = *(const float4*)&BsF[k][128 + to * 4];
            double a[8], b[8];
            a[0] = (double)af0.x; a[1] = (double)af0.y;
            a[2] = (double)af0.z; a[3] = (double)af0.w;
            a[4] = (double)af1.x; a[5] = (double)af1.y;
            a[6] = (double)af1.z; a[7] = (double)af1.w;
            b[0] = (double)bf0.x; b[1] = (double)bf0.y;
            b[2] = (double)bf0.z; b[3] = (double)bf0.w;
            b[4] = (double)bf1.x; b[5] = (double)bf1.y;
            b[6] = (double)bf1.z; b[7] = (double)bf1.w;
#pragma unroll
            for (int i = 0; i < 8; ++i)
#pragma unroll
                for (int j = 0; j < 8; ++j)
                    acc[i][j] += a[i] * b[j];
        }
    }

    double biasd[8];
#pragma unroll
    for (int j = 0; j < 8; ++j)
        biasd[j] = (double)bias[o0 * 256 + (j >> 2) * 128 + to * 4 + (j & 3)];
    double (*trans)[67] = (double(*)[67])smem[0];
    for (int c = 0; c < 16; ++c) {
        __syncthreads();
        const int j4  = c >> 3;
        const int tlo = (c & 7) * 4;
        if (to >= tlo && to < tlo + 4) {
#pragma unroll
            for (int p4 = 0; p4 < 4; ++p4) {
                const int r = (to - tlo) * 4 + p4;
                const int j = j4 * 4 + p4;
#pragma unroll
                for (int i = 0; i < 8; ++i)
                    trans[r][tb * 8 + i] = acc[i][j] + biasd[j];
            }
        }
        __syncthreads();
#pragma unroll
        for (int q = 0; q < 4; ++q) {
            const int idx = tid + 256 * q;
            const int b  = idx & 63;
            const int oc = idx >> 6;
            pre[(size_t)(t0 * DOUT_ + o0 * 256 + c * 16 + oc) * 64 + b] = trans[oc][b];
        }
    }
}

// -----------------------------------------------------------------------------
// Scan: one wave per o, lane = b. Batch-mean via ballot+popcount.
// 16-deep load grouping (~8 MB in flight across 1024 waves) for HBM overlap.
// -----------------------------------------------------------------------------
__global__ __launch_bounds__(256) void snn_scan(
    const double* __restrict__ pre, const float* __restrict__ thr_in,
    unsigned long long* __restrict__ spM, float* __restrict__ outD)
{
    const int wid  = (blockIdx.x * blockDim.x + threadIdx.x) >> 6;
    const int lane = threadIdx.x & 63;
    if (wid >= DOUT_) return;
    const int o = wid;

    double mem = 0.0;
    double thr = (double)thr_in[o];
    const double* p = pre + (size_t)o * 64 + lane;

    for (int t = 0; t < T_; t += 16) {
        double pv[16];
#pragma unroll
        for (int j = 0; j < 16; ++j)
            pv[j] = p[(size_t)(t + j) * (DOUT_ * 64)];
#pragma unroll
        for (int j = 0; j < 16; ++j) {
            mem += pv[j];
            const bool s = (mem >= thr);
            const unsigned long long msk = __ballot(s);
            const int cnt = __popcll(msk);
            thr += 0.05 * ((double)cnt * (1.0 / 64.0) - 0.5);
            if (spM) {
                if (lane == 0) spM[(size_t)(t + j) * DOUT_ + o] = msk;
            } else {
                outD[(size_t)lane * (T_ * DOUT_) + (size_t)(t + j) * DOUT_ + o] =
                    s ? 1.0f : 0.0f;
            }
            mem = s ? 0.0 : mem;
        }
    }
}

__global__ __launch_bounds__(256) void snn_expand(
    const unsigned long long* __restrict__ spM, float* __restrict__ out)
{
    const int r = blockIdx.x * 256 + threadIdx.x;
    const unsigned long long m = spM[r];
#pragma unroll
    for (int b = 0; b < 64; ++b)
        out[(size_t)b * (T_ * DOUT_) + r] = (float)((m >> b) & 1ULL);
}

extern "C" void kernel_launch(void* const* d_in, const int* in_sizes, int n_in,
                              void* d_out, int out_size, void* d_ws, size_t ws_size,
                              hipStream_t stream) {
    const float* x    = (const float*)d_in[0];   // [64][256][1024]
    const float* W    = (const float*)d_in[1];   // [1024][1024]
    const float* bias = (const float*)d_in[2];   // [1024]
    const float* thr  = (const float*)d_in[3];   // [1024]
    float* out = (float*)d_out;                  // [64][256][1024]

    double* pre = (double*)d_ws;
    const size_t need = PRE_BYTES + XS_BYTES + WSL_BYTES + SPM_BYTES;

    if (ws_size >= need) {
        char* xs  = (char*)d_ws + PRE_BYTES;
        char* wsl = xs + XS_BYTES;
        unsigned long long* spM = (unsigned long long*)(wsl + WSL_BYTES);
        snn_split_x<<<4096, 256, 0, stream>>>(x, xs);
        snn_split_w<<<256, 256, 0, stream>>>(W, wsl);
        snn_gemm_i8<<<4096, 256, 0, stream>>>(xs, wsl, bias, pre);
        snn_scan<<<256, 256, 0, stream>>>(pre, thr, spM, nullptr);
        snn_expand<<<1024, 256, 0, stream>>>(spM, out);
    } else {
        const bool two_stage = (ws_size >= PRE_BYTES + SPM_BYTES);
        unsigned long long* spM =
            two_stage ? (unsigned long long*)((char*)d_ws + PRE_BYTES) : nullptr;
        snn_gemm_fb<<<1024, 256, 0, stream>>>(x, W, bias, pre);
        snn_scan<<<256, 256, 0, stream>>>(pre, thr, spM, two_stage ? nullptr : out);
        if (two_stage)
            snn_expand<<<1024, 256, 0, stream>>>(spM, out);
    }
}

// Round 12
// 478.021 us; speedup vs baseline: 1.1767x; 1.1767x over previous
//
#include <hip/hip_runtime.h>

#define B_ 64
#define T_ 256
#define DIN_ 1024
#define DOUT_ 1024

typedef int v4i  __attribute__((ext_vector_type(4)));
typedef int v16i __attribute__((ext_vector_type(16)));

#define PRE_BYTES 134217728ULL   // 256*1024*64*8
#define XS_BYTES  100663296ULL   // 6*256*32*2*1024
#define WSL_BYTES 6291456ULL     // 6*32*32*1024
#define SPM_BYTES 2097152ULL     // 256*1024*8

// -----------------------------------------------------------------------------
// Split x into 6 signed-i8 slices, fixed scale 2^3, MFMA A-frag chunk order:
// chunk(s,t,kt,mt) = 1KB, byte = lane*16+j, lane = kh*32+m,
// element = x[b=mt*32+m][t][kt*32+kh*16+j]. All split steps exact in fp32.
// -----------------------------------------------------------------------------
__global__ __launch_bounds__(256) void snn_split_x(
    const float* __restrict__ x, char* __restrict__ xs)
{
    const int W    = blockIdx.x * 4 + (threadIdx.x >> 6);   // 0..16383
    const int lane = threadIdx.x & 63;
    const int mt = W & 1, kt = (W >> 1) & 31, t0 = W >> 6;
    const int m = lane & 31, kh = lane >> 5;
    const int b = mt * 32 + m;

    const float* src = x + ((size_t)b * T_ + t0) * DIN_ + kt * 32 + kh * 16;
    float f[16];
    *(float4*)(f)      = *(const float4*)(src);
    *(float4*)(f + 4)  = *(const float4*)(src + 4);
    *(float4*)(f + 8)  = *(const float4*)(src + 8);
    *(float4*)(f + 12) = *(const float4*)(src + 12);

    unsigned pk[6][4];
#pragma unroll
    for (int s = 0; s < 6; ++s)
        pk[s][0] = pk[s][1] = pk[s][2] = pk[s][3] = 0u;
#pragma unroll
    for (int j = 0; j < 16; ++j) {
        float v = f[j] * 0.125f;                 // / 2^3 (exact)
#pragma unroll
        for (int s = 0; s < 6; ++s) {
            const float ml = (s == 0) ? 64.f : 128.f;
            const float sv = __builtin_rintf(v * ml);
            v = v * ml - sv;                     // exact residual
            const int iv = (int)sv;
            pk[s][j >> 2] |= ((unsigned)iv & 0xffu) << ((j & 3) * 8);
        }
    }
#pragma unroll
    for (int s = 0; s < 6; ++s) {
        char* dst = xs + (size_t)(((s * 256 + t0) * 32 + kt) * 2 + mt) * 1024
                       + lane * 16;
        *(uint4*)dst = make_uint4(pk[s][0], pk[s][1], pk[s][2], pk[s][3]);
    }
}

// -----------------------------------------------------------------------------
// Split W into 6 i8 slices, fixed scale 2^-2, B-frag chunk order:
// chunk(s,ot,kt) = 1KB, element = W[o=ot*32+n][kt*32+kh*16+j].
// -----------------------------------------------------------------------------
__global__ __launch_bounds__(256) void snn_split_w(
    const float* __restrict__ Wt, char* __restrict__ wsl)
{
    const int W    = blockIdx.x * 4 + (threadIdx.x >> 6);   // 0..1023
    const int lane = threadIdx.x & 63;
    const int kt = W & 31, ot = W >> 5;
    const int n = lane & 31, kh = lane >> 5;
    const int o = ot * 32 + n;

    const float* src = Wt + (size_t)o * DIN_ + kt * 32 + kh * 16;
    float f[16];
    *(float4*)(f)      = *(const float4*)(src);
    *(float4*)(f + 4)  = *(const float4*)(src + 4);
    *(float4*)(f + 8)  = *(const float4*)(src + 8);
    *(float4*)(f + 12) = *(const float4*)(src + 12);

    unsigned pk[6][4];
#pragma unroll
    for (int s = 0; s < 6; ++s)
        pk[s][0] = pk[s][1] = pk[s][2] = pk[s][3] = 0u;
#pragma unroll
    for (int j = 0; j < 16; ++j) {
        float v = f[j] * 4.0f;                   // / 2^-2 (exact)
#pragma unroll
        for (int s = 0; s < 6; ++s) {
            const float ml = (s == 0) ? 64.f : 128.f;
            const float sv = __builtin_rintf(v * ml);
            v = v * ml - sv;
            const int iv = (int)sv;
            pk[s][j >> 2] |= ((unsigned)iv & 0xffu) << ((j & 3) * 8);
        }
    }
#pragma unroll
    for (int s = 0; s < 6; ++s) {
        char* dst = wsl + (size_t)((s * 32 + ot) * 32 + kt) * 1024 + lane * 16;
        *(uint4*)dst = make_uint4(pk[s][0], pk[s][1], pk[s][2], pk[s][3]);
    }
}

// -----------------------------------------------------------------------------
// GEMM via i8 MFMA (round-9 structure, 309 us base). Block (t0, oB): 64b x 64o;
// 4 waves = 2x2 of 32x32 tiles. LDS-staged A+B chunks (24 KB/kt, dbuf, one
// barrier per kt). ONLY change vs R9: MFMA issue order is a-major (i outer,
// j inner) so consecutive MFMAs never write the same accumulator -- R9's
// acc-major order had 15/21 MFMAs issued behind a dependent predecessor
// (dependent latency > issue rate stall). i32 accumulation is
// order-independent -> bit-identical result.
// -----------------------------------------------------------------------------
__global__ __launch_bounds__(256, 2) void snn_gemm_i8(
    const char* __restrict__ xs, const char* __restrict__ wsl,
    const float* __restrict__ bias, double* __restrict__ pre)
{
    __shared__ __align__(16) char lds[2][24 * 1024];
    const int t0 = blockIdx.x & 255;
    const int oB = blockIdx.x >> 8;          // 0..15
    const int tid = threadIdx.x;
    const int w = tid >> 6, lane = tid & 63;
    const int wm = w >> 1, wo = w & 1;

    v16i zero;
#pragma unroll
    for (int r = 0; r < 16; ++r) zero[r] = 0;
    v16i acc[6];
#pragma unroll
    for (int g = 0; g < 6; ++g) acc[g] = zero;

    // each wave stages 6 chunks/kt: waves 0,1 -> A(mt=w), waves 2,3 -> B(ot=w-2)
    const char* src[6];
    int stride, slot0;
    if (w < 2) {
#pragma unroll
        for (int s = 0; s < 6; ++s)
            src[s] = xs + (size_t)(((s * 256 + t0) * 32) * 2 + w) * 1024
                        + lane * 16;
        stride = 2048; slot0 = w * 6;
    } else {
#pragma unroll
        for (int s = 0; s < 6; ++s)
            src[s] = wsl + (size_t)((s * 32 + oB * 2 + (w - 2)) * 32) * 1024
                         + lane * 16;
        stride = 1024; slot0 = 12 + (w - 2) * 6;
    }

    v4i p[6];
#pragma unroll
    for (int s = 0; s < 6; ++s) p[s] = *(const v4i*)(src[s]);

    for (int kt = 0; kt < 32; ++kt) {
        char* buf = lds[kt & 1];
#pragma unroll
        for (int s = 0; s < 6; ++s)
            *(v4i*)(buf + (slot0 + s) * 1024 + lane * 16) = p[s];
        __syncthreads();
        if (kt + 1 < 32) {
#pragma unroll
            for (int s = 0; s < 6; ++s)
                p[s] = *(const v4i*)(src[s] + (size_t)(kt + 1) * stride);
        }
        v4i a[6], b[6];
#pragma unroll
        for (int s = 0; s < 6; ++s) {
            a[s] = *(const v4i*)(buf + (wm * 6 + s) * 1024 + lane * 16);
            b[s] = *(const v4i*)(buf + (12 + wo * 6 + s) * 1024 + lane * 16);
        }
        // a-major: consecutive MFMAs target different acc chains
#pragma unroll
        for (int i = 0; i < 6; ++i) {
#pragma unroll
            for (int j = 0; j < 6 - i; ++j)
                acc[i + j] = __builtin_amdgcn_mfma_i32_32x32x32_i8(
                    a[i], b[j], acc[i + j], 0, 0, 0);
        }
    }

    // epilogue: D layout col=lane&31 (o), row=(r&3)+8*(r>>2)+4*(lane>>5) (b)
    const int n = lane & 31, lh = lane >> 5;
    const int o = oB * 64 + wo * 32 + n;
    const double bv = (double)bias[o];
    double* dst = pre + ((size_t)t0 * DOUT_ + o) * 64 + wm * 32;
#pragma unroll
    for (int r = 0; r < 16; ++r) {
        const int row = (r & 3) + 8 * (r >> 2) + 4 * lh;
        double v = (double)acc[5][r];
        v = v * 0.0078125 + (double)acc[4][r];
        v = v * 0.0078125 + (double)acc[3][r];
        v = v * 0.0078125 + (double)acc[2][r];
        v = v * 0.0078125 + (double)acc[1][r];
        v = v * 0.0078125 + (double)acc[0][r];
        dst[row] = v * 0x1p-11 + bv;             // 2^{3-2-12}
    }
}

// -----------------------------------------------------------------------------
// Fallback GEMM (round-8 proven fp64-VALU path), used when ws is small.
// -----------------------------------------------------------------------------
__global__ __launch_bounds__(256, 2) void snn_gemm_fb(
    const float* __restrict__ x, const float* __restrict__ W,
    const float* __restrict__ bias, double* __restrict__ pre)
{
    __shared__ float smem[2][8 * 72 + 8 * 256];
    const int t0 = blockIdx.x & 255;
    const int o0 = blockIdx.x >> 8;
    const int tid = threadIdx.x;
    const int to = tid & 31;
    const int tb = tid >> 5;

    double acc[8][8];
#pragma unroll
    for (int i = 0; i < 8; ++i)
#pragma unroll
        for (int j = 0; j < 8; ++j) acc[i][j] = 0.0;

    const int arow = tid >> 2;
    const int ak2  = (tid & 3) * 2;
    const float* xg = x + (size_t)(t0 + 256 * arow) * DIN_ + ak2;
    const float* wg = W + (size_t)(o0 * 256 + tid) * DIN_;

    float2 f2  = *(const float2*)(xg);
    float4 bq0 = *(const float4*)(wg);
    float4 bq1 = *(const float4*)(wg + 4);

    for (int kc = 0; kc < DIN_ / 8; ++kc) {
        float* base = smem[kc & 1];
        float (*AsF)[72]  = (float(*)[72])base;
        float (*BsF)[256] = (float(*)[256])(base + 8 * 72);
        AsF[ak2 + 0][arow] = f2.x;
        AsF[ak2 + 1][arow] = f2.y;
        BsF[0][tid] = bq0.x;  BsF[1][tid] = bq0.y;
        BsF[2][tid] = bq0.z;  BsF[3][tid] = bq0.w;
        BsF[4][tid] = bq1.x;  BsF[5][tid] = bq1.y;
        BsF[6][tid] = bq1.z;  BsF[7][tid] = bq1.w;
        __syncthreads();
        if (kc + 1 < DIN_ / 8) {
            f2  = *(const float2*)(xg + (kc + 1) * 8);
            bq0 = *(const float4*)(wg + (kc + 1) * 8);
            bq1 = *(const float4*)(wg + (kc + 1) * 8 + 4);
        }
#pragma unroll
        for (int k = 0; k < 8; ++k) {
            const float4 af0 = *(const float4*)&AsF[k][tb * 8];
            const float4 af1 = *(const float4*)&AsF[k][tb * 8 + 4];
            const float4 bf0 = *(const float4*)&BsF[k][to * 4];
            const float4 bf1 = *(const float4*)&BsF[k][128 + to * 4];
            double a[8], b[8];
            a[0] = (double)af0.x; a[1] = (double)af0.y;
            a[2] = (double)af0.z; a[3] = (double)af0.w;
            a[4] = (double)af1.x; a[5] = (double)af1.y;
            a[6] = (double)af1.z; a[7] = (double)af1.w;
            b[0] = (double)bf0.x; b[1] = (double)bf0.y;
            b[2] = (double)bf0.z; b[3] = (double)bf0.w;
            b[4] = (double)bf1.x; b[5] = (double)bf1.y;
            b[6] = (double)bf1.z; b[7] = (double)bf1.w;
#pragma unroll
            for (int i = 0; i < 8; ++i)
#pragma unroll
                for (int j = 0; j < 8; ++j)
                    acc[i][j] += a[i] * b[j];
        }
    }

    double biasd[8];
#pragma unroll
    for (int j = 0; j < 8; ++j)
        biasd[j] = (double)bias[o0 * 256 + (j >> 2) * 128 + to * 4 + (j & 3)];
    double (*trans)[67] = (double(*)[67])smem[0];
    for (int c = 0; c < 16; ++c) {
        __syncthreads();
        const int j4  = c >> 3;
        const int tlo = (c & 7) * 4;
        if (to >= tlo && to < tlo + 4) {
#pragma unroll
            for (int p4 = 0; p4 < 4; ++p4) {
                const int r = (to - tlo) * 4 + p4;
                const int j = j4 * 4 + p4;
#pragma unroll
                for (int i = 0; i < 8; ++i)
                    trans[r][tb * 8 + i] = acc[i][j] + biasd[j];
            }
        }
        __syncthreads();
#pragma unroll
        for (int q = 0; q < 4; ++q) {
            const int idx = tid + 256 * q;
            const int b  = idx & 63;
            const int oc = idx >> 6;
            pre[(size_t)(t0 * DOUT_ + o0 * 256 + c * 16 + oc) * 64 + b] = trans[oc][b];
        }
    }
}

// -----------------------------------------------------------------------------
// Scan: one wave per o, lane = b. Batch-mean via ballot+popcount.
// 16-deep load grouping (~8 MB in flight across 1024 waves) for HBM overlap.
// -----------------------------------------------------------------------------
__global__ __launch_bounds__(256) void snn_scan(
    const double* __restrict__ pre, const float* __restrict__ thr_in,
    unsigned long long* __restrict__ spM, float* __restrict__ outD)
{
    const int wid  = (blockIdx.x * blockDim.x + threadIdx.x) >> 6;
    const int lane = threadIdx.x & 63;
    if (wid >= DOUT_) return;
    const int o = wid;

    double mem = 0.0;
    double thr = (double)thr_in[o];
    const double* p = pre + (size_t)o * 64 + lane;

    for (int t = 0; t < T_; t += 16) {
        double pv[16];
#pragma unroll
        for (int j = 0; j < 16; ++j)
            pv[j] = p[(size_t)(t + j) * (DOUT_ * 64)];
#pragma unroll
        for (int j = 0; j < 16; ++j) {
            mem += pv[j];
            const bool s = (mem >= thr);
            const unsigned long long msk = __ballot(s);
            const int cnt = __popcll(msk);
            thr += 0.05 * ((double)cnt * (1.0 / 64.0) - 0.5);
            if (spM) {
                if (lane == 0) spM[(size_t)(t + j) * DOUT_ + o] = msk;
            } else {
                outD[(size_t)lane * (T_ * DOUT_) + (size_t)(t + j) * DOUT_ + o] =
                    s ? 1.0f : 0.0f;
            }
            mem = s ? 0.0 : mem;
        }
    }
}

__global__ __launch_bounds__(256) void snn_expand(
    const unsigned long long* __restrict__ spM, float* __restrict__ out)
{
    const int r = blockIdx.x * 256 + threadIdx.x;
    const unsigned long long m = spM[r];
#pragma unroll
    for (int b = 0; b < 64; ++b)
        out[(size_t)b * (T_ * DOUT_) + r] = (float)((m >> b) & 1ULL);
}

extern "C" void kernel_launch(void* const* d_in, const int* in_sizes, int n_in,
                              void* d_out, int out_size, void* d_ws, size_t ws_size,
                              hipStream_t stream) {
    const float* x    = (const float*)d_in[0];   // [64][256][1024]
    const float* W    = (const float*)d_in[1];   // [1024][1024]
    const float* bias = (const float*)d_in[2];   // [1024]
    const float* thr  = (const float*)d_in[3];   // [1024]
    float* out = (float*)d_out;                  // [64][256][1024]

    double* pre = (double*)d_ws;
    const size_t need = PRE_BYTES + XS_BYTES + WSL_BYTES + SPM_BYTES;

    if (ws_size >= need) {
        char* xs  = (char*)d_ws + PRE_BYTES;
        char* wsl = xs + XS_BYTES;
        unsigned long long* spM = (unsigned long long*)(wsl + WSL_BYTES);
        snn_split_x<<<4096, 256, 0, stream>>>(x, xs);
        snn_split_w<<<256, 256, 0, stream>>>(W, wsl);
        snn_gemm_i8<<<4096, 256, 0, stream>>>(xs, wsl, bias, pre);
        snn_scan<<<256, 256, 0, stream>>>(pre, thr, spM, nullptr);
        snn_expand<<<1024, 256, 0, stream>>>(spM, out);
    } else {
        const bool two_stage = (ws_size >= PRE_BYTES + SPM_BYTES);
        unsigned long long* spM =
            two_stage ? (unsigned long long*)((char*)d_ws + PRE_BYTES) : nullptr;
        snn_gemm_fb<<<1024, 256, 0, stream>>>(x, W, bias, pre);
        snn_scan<<<256, 256, 0, stream>>>(pre, thr, spM, two_stage ? nullptr : out);
        if (two_stage)
            snn_expand<<<1024, 256, 0, stream>>>(spM, out);
    }
}

// Round 13
// 467.006 us; speedup vs baseline: 1.2044x; 1.0236x over previous
//
#include <hip/hip_runtime.h>

#define B_ 64
#define T_ 256
#define DIN_ 1024
#define DOUT_ 1024

typedef int v4i  __attribute__((ext_vector_type(4)));
typedef int v16i __attribute__((ext_vector_type(16)));

#define PRE_BYTES 134217728ULL   // 256*1024*64*8
#define XS_BYTES  100663296ULL   // 6*256*32*2*1024
#define WSL_BYTES 6291456ULL     // 6*32*32*1024
#define SPM_BYTES 2097152ULL     // 256*1024*8

// async 16B/lane global->LDS DMA: lane i's 16 B from g+i*16 land at l+i*16
// (HW adds lane*16 on the LDS side; l must be the wave-uniform chunk base).
__device__ __forceinline__ void async_copy16(const void* g, void* l) {
    __builtin_amdgcn_global_load_lds(
        (const __attribute__((address_space(1))) void*)g,
        (__attribute__((address_space(3))) void*)l, 16, 0, 0);
}

// -----------------------------------------------------------------------------
// Split x into 6 signed-i8 slices, fixed scale 2^3, MFMA A-frag chunk order:
// chunk(s,t,kt,mt) = 1KB, byte = lane*16+j, lane = kh*32+m,
// element = x[b=mt*32+m][t][kt*32+kh*16+j]. All split steps exact in fp32.
// -----------------------------------------------------------------------------
__global__ __launch_bounds__(256) void snn_split_x(
    const float* __restrict__ x, char* __restrict__ xs)
{
    const int W    = blockIdx.x * 4 + (threadIdx.x >> 6);   // 0..16383
    const int lane = threadIdx.x & 63;
    const int mt = W & 1, kt = (W >> 1) & 31, t0 = W >> 6;
    const int m = lane & 31, kh = lane >> 5;
    const int b = mt * 32 + m;

    const float* src = x + ((size_t)b * T_ + t0) * DIN_ + kt * 32 + kh * 16;
    float f[16];
    *(float4*)(f)      = *(const float4*)(src);
    *(float4*)(f + 4)  = *(const float4*)(src + 4);
    *(float4*)(f + 8)  = *(const float4*)(src + 8);
    *(float4*)(f + 12) = *(const float4*)(src + 12);

    unsigned pk[6][4];
#pragma unroll
    for (int s = 0; s < 6; ++s)
        pk[s][0] = pk[s][1] = pk[s][2] = pk[s][3] = 0u;
#pragma unroll
    for (int j = 0; j < 16; ++j) {
        float v = f[j] * 0.125f;                 // / 2^3 (exact)
#pragma unroll
        for (int s = 0; s < 6; ++s) {
            const float ml = (s == 0) ? 64.f : 128.f;
            const float sv = __builtin_rintf(v * ml);
            v = v * ml - sv;                     // exact residual
            const int iv = (int)sv;
            pk[s][j >> 2] |= ((unsigned)iv & 0xffu) << ((j & 3) * 8);
        }
    }
#pragma unroll
    for (int s = 0; s < 6; ++s) {
        char* dst = xs + (size_t)(((s * 256 + t0) * 32 + kt) * 2 + mt) * 1024
                       + lane * 16;
        *(uint4*)dst = make_uint4(pk[s][0], pk[s][1], pk[s][2], pk[s][3]);
    }
}

// -----------------------------------------------------------------------------
// Split W into 6 i8 slices, fixed scale 2^-2, B-frag chunk order:
// chunk(s,ot,kt) = 1KB, element = W[o=ot*32+n][kt*32+kh*16+j].
// -----------------------------------------------------------------------------
__global__ __launch_bounds__(256) void snn_split_w(
    const float* __restrict__ Wt, char* __restrict__ wsl)
{
    const int W    = blockIdx.x * 4 + (threadIdx.x >> 6);   // 0..1023
    const int lane = threadIdx.x & 63;
    const int kt = W & 31, ot = W >> 5;
    const int n = lane & 31, kh = lane >> 5;
    const int o = ot * 32 + n;

    const float* src = Wt + (size_t)o * DIN_ + kt * 32 + kh * 16;
    float f[16];
    *(float4*)(f)      = *(const float4*)(src);
    *(float4*)(f + 4)  = *(const float4*)(src + 4);
    *(float4*)(f + 8)  = *(const float4*)(src + 8);
    *(float4*)(f + 12) = *(const float4*)(src + 12);

    unsigned pk[6][4];
#pragma unroll
    for (int s = 0; s < 6; ++s)
        pk[s][0] = pk[s][1] = pk[s][2] = pk[s][3] = 0u;
#pragma unroll
    for (int j = 0; j < 16; ++j) {
        float v = f[j] * 4.0f;                   // / 2^-2 (exact)
#pragma unroll
        for (int s = 0; s < 6; ++s) {
            const float ml = (s == 0) ? 64.f : 128.f;
            const float sv = __builtin_rintf(v * ml);
            v = v * ml - sv;
            const int iv = (int)sv;
            pk[s][j >> 2] |= ((unsigned)iv & 0xffu) << ((j & 3) * 8);
        }
    }
#pragma unroll
    for (int s = 0; s < 6; ++s) {
        char* dst = wsl + (size_t)((s * 32 + ot) * 32 + kt) * 1024 + lane * 16;
        *(uint4*)dst = make_uint4(pk[s][0], pk[s][1], pk[s][2], pk[s][3]);
    }
}

// -----------------------------------------------------------------------------
// GEMM via i8 MFMA. R9 tiling (block = 64b x 64o, 4 waves 2x2, 21 exact
// slice-pair MFMAs into 6 i32 accs) but staged by async global_load_lds DMA:
// no VGPR prefetch buffers -> unified regs fit 3 waves/SIMD (launch_bounds
// (256,3)); LDS 48 KB x 3 blocks = 144 <= 160 KB. One barrier per kt:
// compiler's vmcnt(0)-before-s_barrier drains the kt DMA; the post-barrier
// DMA targets the buffer whose readers all finished before the barrier.
// -----------------------------------------------------------------------------
__global__ __launch_bounds__(256, 3) void snn_gemm_i8(
    const char* __restrict__ xs, const char* __restrict__ wsl,
    const float* __restrict__ bias, double* __restrict__ pre)
{
    __shared__ __align__(16) char lds[2][24 * 1024];
    const int t0 = blockIdx.x & 255;
    const int oB = blockIdx.x >> 8;          // 0..15
    const int tid = threadIdx.x;
    const int lane = tid & 63;
    const int ws = __builtin_amdgcn_readfirstlane(tid >> 6);   // scalar wave id
    const int wmS = ws >> 1, woS = ws & 1;

    v16i zero;
#pragma unroll
    for (int r = 0; r < 16; ++r) zero[r] = 0;
    v16i acc[6];
#pragma unroll
    for (int g = 0; g < 6; ++g) acc[g] = zero;

    // DMA sources: waves 0,1 stage A (mt = ws), waves 2,3 stage B (ot = ws-2).
    // All-scalar base (SGPR) + lane*16 voffset; s-stride/kt-stride scalar.
    const char* gbase;
    size_t sStride;
    int ktStride, slot0;
    if (ws < 2) {
        gbase   = xs + ((size_t)t0 * 32 * 2 + ws) * 1024;      // s=0, kt=0
        sStride = 16777216;                                    // 256*32*2*1024
        ktStride = 2048;
        slot0 = ws * 6;
    } else {
        gbase   = wsl + (size_t)(oB * 2 + (ws - 2)) * 32 * 1024;
        sStride = 1048576;                                     // 32*32*1024
        ktStride = 1024;
        slot0 = 12 + (ws - 2) * 6;
    }
    const int lo = lane * 16;

    // preload kt=0 into buffer 0
#pragma unroll
    for (int s = 0; s < 6; ++s)
        async_copy16(gbase + (size_t)s * sStride + lo,
                     &lds[0][(slot0 + s) * 1024]);

    for (int kt = 0; kt < 32; ++kt) {
        __syncthreads();   // vmcnt(0) drain of kt's DMA + cross-wave visibility
        if (kt + 1 < 32) { // stage kt+1 into the other buffer (readers done)
            const char* gn = gbase + (size_t)(kt + 1) * ktStride;
#pragma unroll
            for (int s = 0; s < 6; ++s)
                async_copy16(gn + (size_t)s * sStride + lo,
                             &lds[(kt + 1) & 1][(slot0 + s) * 1024]);
        }
        const char* abase = &lds[kt & 1][(wmS * 6) * 1024] + lo;
        const char* bbase = &lds[kt & 1][(12 + woS * 6) * 1024] + lo;
        v4i a[6], b[6];
#pragma unroll
        for (int s = 0; s < 6; ++s) {
            a[s] = *(const v4i*)(abase + s * 1024);
            b[s] = *(const v4i*)(bbase + s * 1024);
        }
#pragma unroll
        for (int i = 0; i < 6; ++i) {
#pragma unroll
            for (int j = 0; j < 6 - i; ++j)
                acc[i + j] = __builtin_amdgcn_mfma_i32_32x32x32_i8(
                    a[i], b[j], acc[i + j], 0, 0, 0);
        }
    }

    // epilogue: D layout col=lane&31 (o), row=(r&3)+8*(r>>2)+4*(lane>>5) (b)
    const int n = lane & 31, lh = lane >> 5;
    const int o = oB * 64 + woS * 32 + n;
    const double bv = (double)bias[o];
    double* dst = pre + ((size_t)t0 * DOUT_ + o) * 64 + wmS * 32;
#pragma unroll
    for (int r = 0; r < 16; ++r) {
        const int row = (r & 3) + 8 * (r >> 2) + 4 * lh;
        double v = (double)acc[5][r];
        v = v * 0.0078125 + (double)acc[4][r];
        v = v * 0.0078125 + (double)acc[3][r];
        v = v * 0.0078125 + (double)acc[2][r];
        v = v * 0.0078125 + (double)acc[1][r];
        v = v * 0.0078125 + (double)acc[0][r];
        dst[row] = v * 0x1p-11 + bv;             // 2^{3-2-12}
    }
}

// -----------------------------------------------------------------------------
// Fallback GEMM (round-8 proven fp64-VALU path), used when ws is small.
// -----------------------------------------------------------------------------
__global__ __launch_bounds__(256, 2) void snn_gemm_fb(
    const float* __restrict__ x, const float* __restrict__ W,
    const float* __restrict__ bias, double* __restrict__ pre)
{
    __shared__ float smem[2][8 * 72 + 8 * 256];
    const int t0 = blockIdx.x & 255;
    const int o0 = blockIdx.x >> 8;
    const int tid = threadIdx.x;
    const int to = tid & 31;
    const int tb = tid >> 5;

    double acc[8][8];
#pragma unroll
    for (int i = 0; i < 8; ++i)
#pragma unroll
        for (int j = 0; j < 8; ++j) acc[i][j] = 0.0;

    const int arow = tid >> 2;
    const int ak2  = (tid & 3) * 2;
    const float* xg = x + (size_t)(t0 + 256 * arow) * DIN_ + ak2;
    const float* wg = W + (size_t)(o0 * 256 + tid) * DIN_;

    float2 f2  = *(const float2*)(xg);
    float4 bq0 = *(const float4*)(wg);
    float4 bq1 = *(const float4*)(wg + 4);

    for (int kc = 0; kc < DIN_ / 8; ++kc) {
        float* base = smem[kc & 1];
        float (*AsF)[72]  = (float(*)[72])base;
        float (*BsF)[256] = (float(*)[256])(base + 8 * 72);
        AsF[ak2 + 0][arow] = f2.x;
        AsF[ak2 + 1][arow] = f2.y;
        BsF[0][tid] = bq0.x;  BsF[1][tid] = bq0.y;
        BsF[2][tid] = bq0.z;  BsF[3][tid] = bq0.w;
        BsF[4][tid] = bq1.x;  BsF[5][tid] = bq1.y;
        BsF[6][tid] = bq1.z;  BsF[7][tid] = bq1.w;
        __syncthreads();
        if (kc + 1 < DIN_ / 8) {
            f2  = *(const float2*)(xg + (kc + 1) * 8);
            bq0 = *(const float4*)(wg + (kc + 1) * 8);
            bq1 = *(const float4*)(wg + (kc + 1) * 8 + 4);
        }
#pragma unroll
        for (int k = 0; k < 8; ++k) {
            const float4 af0 = *(const float4*)&AsF[k][tb * 8];
            const float4 af1 = *(const float4*)&AsF[k][tb * 8 + 4];
            const float4 bf0 = *(const float4*)&BsF[k][to * 4];
            const float4 bf1 = *(const float4*)&BsF[k][128 + to * 4];
            double a[8], b[8];
            a[0] = (double)af0.x; a[1] = (double)af0.y;
            a[2] = (double)af0.z; a[3] = (double)af0.w;
            a[4] = (double)af1.x; a[5] = (double)af1.y;
            a[6] = (double)af1.z; a[7] = (double)af1.w;
            b[0] = (double)bf0.x; b[1] = (double)bf0.y;
            b[2] = (double)bf0.z; b[3] = (double)bf0.w;
            b[4] = (double)bf1.x; b[5] = (double)bf1.y;
            b[6] = (double)bf1.z; b[7] = (double)bf1.w;
#pragma unroll
            for (int i = 0; i < 8; ++i)
#pragma unroll
                for (int j = 0; j < 8; ++j)
                    acc[i][j] += a[i] * b[j];
        }
    }

    double biasd[8];
#pragma unroll
    for (int j = 0; j < 8; ++j)
        biasd[j] = (double)bias[o0 * 256 + (j >> 2) * 128 + to * 4 + (j & 3)];
    double (*trans)[67] = (double(*)[67])smem[0];
    for (int c = 0; c < 16; ++c) {
        __syncthreads();
        const int j4  = c >> 3;
        const int tlo = (c & 7) * 4;
        if (to >= tlo && to < tlo + 4) {
#pragma unroll
            for (int p4 = 0; p4 < 4; ++p4) {
                const int r = (to - tlo) * 4 + p4;
                const int j = j4 * 4 + p4;
#pragma unroll
                for (int i = 0; i < 8; ++i)
                    trans[r][tb * 8 + i] = acc[i][j] + biasd[j];
            }
        }
        __syncthreads();
#pragma unroll
        for (int q = 0; q < 4; ++q) {
            const int idx = tid + 256 * q;
            const int b  = idx & 63;
            const int oc = idx >> 6;
            pre[(size_t)(t0 * DOUT_ + o0 * 256 + c * 16 + oc) * 64 + b] = trans[oc][b];
        }
    }
}

// -----------------------------------------------------------------------------
// Scan: one wave per o, lane = b. Batch-mean via ballot+popcount.
// 16-deep load grouping (~8 MB in flight across 1024 waves) for HBM overlap.
// -----------------------------------------------------------------------------
__global__ __launch_bounds__(256) void snn_scan(
    const double* __restrict__ pre, const float* __restrict__ thr_in,
    unsigned long long* __restrict__ spM, float* __restrict__ outD)
{
    const int wid  = (blockIdx.x * blockDim.x + threadIdx.x) >> 6;
    const int lane = threadIdx.x & 63;
    if (wid >= DOUT_) return;
    const int o = wid;

    double mem = 0.0;
    double thr = (double)thr_in[o];
    const double* p = pre + (size_t)o * 64 + lane;

    for (int t = 0; t < T_; t += 16) {
        double pv[16];
#pragma unroll
        for (int j = 0; j < 16; ++j)
            pv[j] = p[(size_t)(t + j) * (DOUT_ * 64)];
#pragma unroll
        for (int j = 0; j < 16; ++j) {
            mem += pv[j];
            const bool s = (mem >= thr);
            const unsigned long long msk = __ballot(s);
            const int cnt = __popcll(msk);
            thr += 0.05 * ((double)cnt * (1.0 / 64.0) - 0.5);
            if (spM) {
                if (lane == 0) spM[(size_t)(t + j) * DOUT_ + o] = msk;
            } else {
                outD[(size_t)lane * (T_ * DOUT_) + (size_t)(t + j) * DOUT_ + o] =
                    s ? 1.0f : 0.0f;
            }
            mem = s ? 0.0 : mem;
        }
    }
}

__global__ __launch_bounds__(256) void snn_expand(
    const unsigned long long* __restrict__ spM, float* __restrict__ out)
{
    const int r = blockIdx.x * 256 + threadIdx.x;
    const unsigned long long m = spM[r];
#pragma unroll
    for (int b = 0; b < 64; ++b)
        out[(size_t)b * (T_ * DOUT_) + r] = (float)((m >> b) & 1ULL);
}

extern "C" void kernel_launch(void* const* d_in, const int* in_sizes, int n_in,
                              void* d_out, int out_size, void* d_ws, size_t ws_size,
                              hipStream_t stream) {
    const float* x    = (const float*)d_in[0];   // [64][256][1024]
    const float* W    = (const float*)d_in[1];   // [1024][1024]
    const float* bias = (const float*)d_in[2];   // [1024]
    const float* thr  = (const float*)d_in[3];   // [1024]
    float* out = (float*)d_out;                  // [64][256][1024]

    double* pre = (double*)d_ws;
    const size_t need = PRE_BYTES + XS_BYTES + WSL_BYTES + SPM_BYTES;

    if (ws_size >= need) {
        char* xs  = (char*)d_ws + PRE_BYTES;
        char* wsl = xs + XS_BYTES;
        unsigned long long* spM = (unsigned long long*)(wsl + WSL_BYTES);
        snn_split_x<<<4096, 256, 0, stream>>>(x, xs);
        snn_split_w<<<256, 256, 0, stream>>>(W, wsl);
        snn_gemm_i8<<<4096, 256, 0, stream>>>(xs, wsl, bias, pre);
        snn_scan<<<256, 256, 0, stream>>>(pre, thr, spM, nullptr);
        snn_expand<<<1024, 256, 0, stream>>>(spM, out);
    } else {
        const bool two_stage = (ws_size >= PRE_BYTES + SPM_BYTES);
        unsigned long long* spM =
            two_stage ? (unsigned long long*)((char*)d_ws + PRE_BYTES) : nullptr;
        snn_gemm_fb<<<1024, 256, 0, stream>>>(x, W, bias, pre);
        snn_scan<<<256, 256, 0, stream>>>(pre, thr, spM, two_stage ? nullptr : out);
        if (two_stage)
            snn_expand<<<1024, 256, 0, stream>>>(spM, out);
    }
}

// Round 14
// 407.545 us; speedup vs baseline: 1.3802x; 1.1459x over previous
//
#include <hip/hip_runtime.h>

#define B_ 64
#define T_ 256
#define DIN_ 1024
#define DOUT_ 1024

typedef int v4i  __attribute__((ext_vector_type(4)));
typedef int v16i __attribute__((ext_vector_type(16)));

#define PRE_BYTES 134217728ULL   // 256*1024*64*8
#define XS_BYTES  83886080ULL    // 5*256*32*2*1024
#define WSL_BYTES 5242880ULL     // 5*32*32*1024
#define SPM_BYTES 2097152ULL     // 256*1024*8

// async 16B/lane global->LDS DMA: lane i's 16 B from g+i*16 land at l+i*16.
__device__ __forceinline__ void async_copy16(const void* g, void* l) {
    __builtin_amdgcn_global_load_lds(
        (const __attribute__((address_space(1))) void*)g,
        (__attribute__((address_space(3))) void*)l, 16, 0, 0);
}

// -----------------------------------------------------------------------------
// Split x into 5 signed-i8 slices, fixed scale 2^3, MFMA A-frag chunk order:
// chunk(s,t,kt,mt) = 1KB, byte = lane*16+j, lane = kh*32+m,
// element = x[b=mt*32+m][t][kt*32+kh*16+j]. 5 slices capture 34 bits:
// any |v|>=2^-8 exactly (fp32 has 24-bit mantissa); residual <= 2^-32.
// -----------------------------------------------------------------------------
__global__ __launch_bounds__(256) void snn_split_x(
    const float* __restrict__ x, char* __restrict__ xs)
{
    const int W    = blockIdx.x * 4 + (threadIdx.x >> 6);   // 0..16383
    const int lane = threadIdx.x & 63;
    const int mt = W & 1, kt = (W >> 1) & 31, t0 = W >> 6;
    const int m = lane & 31, kh = lane >> 5;
    const int b = mt * 32 + m;

    const float* src = x + ((size_t)b * T_ + t0) * DIN_ + kt * 32 + kh * 16;
    float f[16];
    *(float4*)(f)      = *(const float4*)(src);
    *(float4*)(f + 4)  = *(const float4*)(src + 4);
    *(float4*)(f + 8)  = *(const float4*)(src + 8);
    *(float4*)(f + 12) = *(const float4*)(src + 12);

    unsigned pk[5][4];
#pragma unroll
    for (int s = 0; s < 5; ++s)
        pk[s][0] = pk[s][1] = pk[s][2] = pk[s][3] = 0u;
#pragma unroll
    for (int j = 0; j < 16; ++j) {
        float v = f[j] * 0.125f;                 // / 2^3 (exact)
#pragma unroll
        for (int s = 0; s < 5; ++s) {
            const float ml = (s == 0) ? 64.f : 128.f;
            const float sv = __builtin_rintf(v * ml);
            v = v * ml - sv;                     // exact residual
            const int iv = (int)sv;
            pk[s][j >> 2] |= ((unsigned)iv & 0xffu) << ((j & 3) * 8);
        }
    }
#pragma unroll
    for (int s = 0; s < 5; ++s) {
        char* dst = xs + (size_t)(((s * 256 + t0) * 32 + kt) * 2 + mt) * 1024
                       + lane * 16;
        *(uint4*)dst = make_uint4(pk[s][0], pk[s][1], pk[s][2], pk[s][3]);
    }
}

// -----------------------------------------------------------------------------
// Split W into 5 i8 slices, fixed scale 2^-2, B-frag chunk order:
// chunk(s,ot,kt) = 1KB, element = W[o=ot*32+n][kt*32+kh*16+j].
// -----------------------------------------------------------------------------
__global__ __launch_bounds__(256) void snn_split_w(
    const float* __restrict__ Wt, char* __restrict__ wsl)
{
    const int W    = blockIdx.x * 4 + (threadIdx.x >> 6);   // 0..1023
    const int lane = threadIdx.x & 63;
    const int kt = W & 31, ot = W >> 5;
    const int n = lane & 31, kh = lane >> 5;
    const int o = ot * 32 + n;

    const float* src = Wt + (size_t)o * DIN_ + kt * 32 + kh * 16;
    float f[16];
    *(float4*)(f)      = *(const float4*)(src);
    *(float4*)(f + 4)  = *(const float4*)(src + 4);
    *(float4*)(f + 8)  = *(const float4*)(src + 8);
    *(float4*)(f + 12) = *(const float4*)(src + 12);

    unsigned pk[5][4];
#pragma unroll
    for (int s = 0; s < 5; ++s)
        pk[s][0] = pk[s][1] = pk[s][2] = pk[s][3] = 0u;
#pragma unroll
    for (int j = 0; j < 16; ++j) {
        float v = f[j] * 4.0f;                   // / 2^-2 (exact)
#pragma unroll
        for (int s = 0; s < 5; ++s) {
            const float ml = (s == 0) ? 64.f : 128.f;
            const float sv = __builtin_rintf(v * ml);
            v = v * ml - sv;
            const int iv = (int)sv;
            pk[s][j >> 2] |= ((unsigned)iv & 0xffu) << ((j & 3) * 8);
        }
    }
#pragma unroll
    for (int s = 0; s < 5; ++s) {
        char* dst = wsl + (size_t)((s * 32 + ot) * 32 + kt) * 1024 + lane * 16;
        *(uint4*)dst = make_uint4(pk[s][0], pk[s][1], pk[s][2], pk[s][3]);
    }
}

// -----------------------------------------------------------------------------
// GEMM via i8 MFMA. 5 slices -> 15 pair-MFMAs (i+j<=4) per kt per wave
// (-29% vs 6-slice/21). DMA staging (R13), LDS 2x20KB, one barrier per kt.
// blockIdx = t0*16 + oB: 16 blocks sharing A are dispatch-adjacent -> the
// DMA drain hits L2 (~200cyc) not HBM (~900cyc).
// -----------------------------------------------------------------------------
__global__ __launch_bounds__(256, 3) void snn_gemm_i8(
    const char* __restrict__ xs, const char* __restrict__ wsl,
    const float* __restrict__ bias, double* __restrict__ pre)
{
    __shared__ __align__(16) char lds[2][20 * 1024];
    const int t0 = blockIdx.x >> 4;          // A-reuse swizzle
    const int oB = blockIdx.x & 15;
    const int tid = threadIdx.x;
    const int lane = tid & 63;
    const int ws = __builtin_amdgcn_readfirstlane(tid >> 6);   // scalar wave id
    const int wmS = ws >> 1, woS = ws & 1;

    v16i zero;
#pragma unroll
    for (int r = 0; r < 16; ++r) zero[r] = 0;
    v16i acc[5];
#pragma unroll
    for (int g = 0; g < 5; ++g) acc[g] = zero;

    // DMA sources: waves 0,1 stage A (mt = ws), waves 2,3 stage B (ot = ws-2).
    const char* gbase;
    size_t sStride;
    int ktStride, slot0;
    if (ws < 2) {
        gbase   = xs + ((size_t)t0 * 32 * 2 + ws) * 1024;      // s=0, kt=0
        sStride = 16777216;                                    // 256*32*2*1024
        ktStride = 2048;
        slot0 = ws * 5;
    } else {
        gbase   = wsl + (size_t)(oB * 2 + (ws - 2)) * 32 * 1024;
        sStride = 1048576;                                     // 32*32*1024
        ktStride = 1024;
        slot0 = 10 + (ws - 2) * 5;
    }
    const int lo = lane * 16;

    // preload kt=0 into buffer 0
#pragma unroll
    for (int s = 0; s < 5; ++s)
        async_copy16(gbase + (size_t)s * sStride + lo,
                     &lds[0][(slot0 + s) * 1024]);

    for (int kt = 0; kt < 32; ++kt) {
        __syncthreads();   // vmcnt(0) drain of kt's DMA + cross-wave visibility
        if (kt + 1 < 32) { // stage kt+1 into the other buffer (readers done)
            const char* gn = gbase + (size_t)(kt + 1) * ktStride;
#pragma unroll
            for (int s = 0; s < 5; ++s)
                async_copy16(gn + (size_t)s * sStride + lo,
                             &lds[(kt + 1) & 1][(slot0 + s) * 1024]);
        }
        const char* abase = &lds[kt & 1][(wmS * 5) * 1024] + lo;
        const char* bbase = &lds[kt & 1][(10 + woS * 5) * 1024] + lo;
        v4i a[5], b[5];
#pragma unroll
        for (int s = 0; s < 5; ++s) {
            a[s] = *(const v4i*)(abase + s * 1024);
            b[s] = *(const v4i*)(bbase + s * 1024);
        }
#pragma unroll
        for (int i = 0; i < 5; ++i) {
#pragma unroll
            for (int j = 0; j < 5 - i; ++j)
                acc[i + j] = __builtin_amdgcn_mfma_i32_32x32x32_i8(
                    a[i], b[j], acc[i + j], 0, 0, 0);
        }
    }

    // epilogue: D layout col=lane&31 (o), row=(r&3)+8*(r>>2)+4*(lane>>5) (b)
    const int n = lane & 31, lh = lane >> 5;
    const int o = oB * 64 + woS * 32 + n;
    const double bv = (double)bias[o];
    double* dst = pre + ((size_t)t0 * DOUT_ + o) * 64 + wmS * 32;
#pragma unroll
    for (int r = 0; r < 16; ++r) {
        const int row = (r & 3) + 8 * (r >> 2) + 4 * lh;
        double v = (double)acc[4][r];
        v = v * 0.0078125 + (double)acc[3][r];
        v = v * 0.0078125 + (double)acc[2][r];
        v = v * 0.0078125 + (double)acc[1][r];
        v = v * 0.0078125 + (double)acc[0][r];
        dst[row] = v * 0x1p-11 + bv;             // 2^{3-2-12}
    }
}

// -----------------------------------------------------------------------------
// Fallback GEMM (round-8 proven fp64-VALU path), used when ws is small.
// -----------------------------------------------------------------------------
__global__ __launch_bounds__(256, 2) void snn_gemm_fb(
    const float* __restrict__ x, const float* __restrict__ W,
    const float* __restrict__ bias, double* __restrict__ pre)
{
    __shared__ float smem[2][8 * 72 + 8 * 256];
    const int t0 = blockIdx.x & 255;
    const int o0 = blockIdx.x >> 8;
    const int tid = threadIdx.x;
    const int to = tid & 31;
    const int tb = tid >> 5;

    double acc[8][8];
#pragma unroll
    for (int i = 0; i < 8; ++i)
#pragma unroll
        for (int j = 0; j < 8; ++j) acc[i][j] = 0.0;

    const int arow = tid >> 2;
    const int ak2  = (tid & 3) * 2;
    const float* xg = x + (size_t)(t0 + 256 * arow) * DIN_ + ak2;
    const float* wg = W + (size_t)(o0 * 256 + tid) * DIN_;

    float2 f2  = *(const float2*)(xg);
    float4 bq0 = *(const float4*)(wg);
    float4 bq1 = *(const float4*)(wg + 4);

    for (int kc = 0; kc < DIN_ / 8; ++kc) {
        float* base = smem[kc & 1];
        float (*AsF)[72]  = (float(*)[72])base;
        float (*BsF)[256] = (float(*)[256])(base + 8 * 72);
        AsF[ak2 + 0][arow] = f2.x;
        AsF[ak2 + 1][arow] = f2.y;
        BsF[0][tid] = bq0.x;  BsF[1][tid] = bq0.y;
        BsF[2][tid] = bq0.z;  BsF[3][tid] = bq0.w;
        BsF[4][tid] = bq1.x;  BsF[5][tid] = bq1.y;
        BsF[6][tid] = bq1.z;  BsF[7][tid] = bq1.w;
        __syncthreads();
        if (kc + 1 < DIN_ / 8) {
            f2  = *(const float2*)(xg + (kc + 1) * 8);
            bq0 = *(const float4*)(wg + (kc + 1) * 8);
            bq1 = *(const float4*)(wg + (kc + 1) * 8 + 4);
        }
#pragma unroll
        for (int k = 0; k < 8; ++k) {
            const float4 af0 = *(const float4*)&AsF[k][tb * 8];
            const float4 af1 = *(const float4*)&AsF[k][tb * 8 + 4];
            const float4 bf0 = *(const float4*)&BsF[k][to * 4];
            const float4 bf1 = *(const float4*)&BsF[k][128 + to * 4];
            double a[8], b[8];
            a[0] = (double)af0.x; a[1] = (double)af0.y;
            a[2] = (double)af0.z; a[3] = (double)af0.w;
            a[4] = (double)af1.x; a[5] = (double)af1.y;
            a[6] = (double)af1.z; a[7] = (double)af1.w;
            b[0] = (double)bf0.x; b[1] = (double)bf0.y;
            b[2] = (double)bf0.z; b[3] = (double)bf0.w;
            b[4] = (double)bf1.x; b[5] = (double)bf1.y;
            b[6] = (double)bf1.z; b[7] = (double)bf1.w;
#pragma unroll
            for (int i = 0; i < 8; ++i)
#pragma unroll
                for (int j = 0; j < 8; ++j)
                    acc[i][j] += a[i] * b[j];
        }
    }

    double biasd[8];
#pragma unroll
    for (int j = 0; j < 8; ++j)
        biasd[j] = (double)bias[o0 * 256 + (j >> 2) * 128 + to * 4 + (j & 3)];
    double (*trans)[67] = (double(*)[67])smem[0];
    for (int c = 0; c < 16; ++c) {
        __syncthreads();
        const int j4  = c >> 3;
        const int tlo = (c & 7) * 4;
        if (to >= tlo && to < tlo + 4) {
#pragma unroll
            for (int p4 = 0; p4 < 4; ++p4) {
                const int r = (to - tlo) * 4 + p4;
                const int j = j4 * 4 + p4;
#pragma unroll
                for (int i = 0; i < 8; ++i)
                    trans[r][tb * 8 + i] = acc[i][j] + biasd[j];
            }
        }
        __syncthreads();
#pragma unroll
        for (int q = 0; q < 4; ++q) {
            const int idx = tid + 256 * q;
            const int b  = idx & 63;
            const int oc = idx >> 6;
            pre[(size_t)(t0 * DOUT_ + o0 * 256 + c * 16 + oc) * 64 + b] = trans[oc][b];
        }
    }
}

// -----------------------------------------------------------------------------
// Scan: one wave per o, lane = b. Batch-mean via ballot+popcount.
// 16-deep load grouping (~8 MB in flight across 1024 waves) for HBM overlap.
// -----------------------------------------------------------------------------
__global__ __launch_bounds__(256) void snn_scan(
    const double* __restrict__ pre, const float* __restrict__ thr_in,
    unsigned long long* __restrict__ spM, float* __restrict__ outD)
{
    const int wid  = (blockIdx.x * blockDim.x + threadIdx.x) >> 6;
    const int lane = threadIdx.x & 63;
    if (wid >= DOUT_) return;
    const int o = wid;

    double mem = 0.0;
    double thr = (double)thr_in[o];
    const double* p = pre + (size_t)o * 64 + lane;

    for (int t = 0; t < T_; t += 16) {
        double pv[16];
#pragma unroll
        for (int j = 0; j < 16; ++j)
            pv[j] = p[(size_t)(t + j) * (DOUT_ * 64)];
#pragma unroll
        for (int j = 0; j < 16; ++j) {
            mem += pv[j];
            const bool s = (mem >= thr);
            const unsigned long long msk = __ballot(s);
            const int cnt = __popcll(msk);
            thr += 0.05 * ((double)cnt * (1.0 / 64.0) - 0.5);
            if (spM) {
                if (lane == 0) spM[(size_t)(t + j) * DOUT_ + o] = msk;
            } else {
                outD[(size_t)lane * (T_ * DOUT_) + (size_t)(t + j) * DOUT_ + o] =
                    s ? 1.0f : 0.0f;
            }
            mem = s ? 0.0 : mem;
        }
    }
}

__global__ __launch_bounds__(256) void snn_expand(
    const unsigned long long* __restrict__ spM, float* __restrict__ out)
{
    const int r = blockIdx.x * 256 + threadIdx.x;
    const unsigned long long m = spM[r];
#pragma unroll
    for (int b = 0; b < 64; ++b)
        out[(size_t)b * (T_ * DOUT_) + r] = (float)((m >> b) & 1ULL);
}

extern "C" void kernel_launch(void* const* d_in, const int* in_sizes, int n_in,
                              void* d_out, int out_size, void* d_ws, size_t ws_size,
                              hipStream_t stream) {
    const float* x    = (const float*)d_in[0];   // [64][256][1024]
    const float* W    = (const float*)d_in[1];   // [1024][1024]
    const float* bias = (const float*)d_in[2];   // [1024]
    const float* thr  = (const float*)d_in[3];   // [1024]
    float* out = (float*)d_out;                  // [64][256][1024]

    double* pre = (double*)d_ws;
    const size_t need = PRE_BYTES + XS_BYTES + WSL_BYTES + SPM_BYTES;

    if (ws_size >= need) {
        char* xs  = (char*)d_ws + PRE_BYTES;
        char* wsl = xs + XS_BYTES;
        unsigned long long* spM = (unsigned long long*)(wsl + WSL_BYTES);
        snn_split_x<<<4096, 256, 0, stream>>>(x, xs);
        snn_split_w<<<256, 256, 0, stream>>>(W, wsl);
        snn_gemm_i8<<<4096, 256, 0, stream>>>(xs, wsl, bias, pre);
        snn_scan<<<256, 256, 0, stream>>>(pre, thr, spM, nullptr);
        snn_expand<<<1024, 256, 0, stream>>>(spM, out);
    } else {
        const bool two_stage = (ws_size >= PRE_BYTES + SPM_BYTES);
        unsigned long long* spM =
            two_stage ? (unsigned long long*)((char*)d_ws + PRE_BYTES) : nullptr;
        snn_gemm_fb<<<1024, 256, 0, stream>>>(x, W, bias, pre);
        snn_scan<<<256, 256, 0, stream>>>(pre, thr, spM, two_stage ? nullptr : out);
        if (two_stage)
            snn_expand<<<1024, 256, 0, stream>>>(spM, out);
    }
}

// Round 15
// 396.180 us; speedup vs baseline: 1.4197x; 1.0287x over previous
//
#include <hip/hip_runtime.h>

#define B_ 64
#define T_ 256
#define DIN_ 1024
#define DOUT_ 1024

typedef int v4i  __attribute__((ext_vector_type(4)));
typedef int v16i __attribute__((ext_vector_type(16)));

#define PRE_BYTES 134217728ULL   // 256*1024*64*8
#define XS_BYTES  83886080ULL    // 5*256*32*2*1024
#define WSL_BYTES 5242880ULL     // 5*32*32*1024
#define SPM_BYTES 2097152ULL     // 256*1024*8

// async 16B/lane global->LDS DMA: lane i's 16 B from g+i*16 land at l+i*16.
__device__ __forceinline__ void async_copy16(const void* g, void* l) {
    __builtin_amdgcn_global_load_lds(
        (const __attribute__((address_space(1))) void*)g,
        (__attribute__((address_space(3))) void*)l, 16, 0, 0);
}

// -----------------------------------------------------------------------------
// Split x into 5 signed-i8 slices, fixed scale 2^3, MFMA A-frag chunk order:
// chunk(s,t,kt,mt) = 1KB, byte = lane*16+j, lane = kh*32+m,
// element = x[b=mt*32+m][t][kt*32+kh*16+j]. 5 slices = 34 bits >= fp32's 24;
// residual <= 2^-32 absolute.
// -----------------------------------------------------------------------------
__global__ __launch_bounds__(256) void snn_split_x(
    const float* __restrict__ x, char* __restrict__ xs)
{
    const int W    = blockIdx.x * 4 + (threadIdx.x >> 6);   // 0..16383
    const int lane = threadIdx.x & 63;
    const int mt = W & 1, kt = (W >> 1) & 31, t0 = W >> 6;
    const int m = lane & 31, kh = lane >> 5;
    const int b = mt * 32 + m;

    const float* src = x + ((size_t)b * T_ + t0) * DIN_ + kt * 32 + kh * 16;
    float f[16];
    *(float4*)(f)      = *(const float4*)(src);
    *(float4*)(f + 4)  = *(const float4*)(src + 4);
    *(float4*)(f + 8)  = *(const float4*)(src + 8);
    *(float4*)(f + 12) = *(const float4*)(src + 12);

    unsigned pk[5][4];
#pragma unroll
    for (int s = 0; s < 5; ++s)
        pk[s][0] = pk[s][1] = pk[s][2] = pk[s][3] = 0u;
#pragma unroll
    for (int j = 0; j < 16; ++j) {
        float v = f[j] * 0.125f;                 // / 2^3 (exact)
#pragma unroll
        for (int s = 0; s < 5; ++s) {
            const float ml = (s == 0) ? 64.f : 128.f;
            const float sv = __builtin_rintf(v * ml);
            v = v * ml - sv;                     // exact residual
            const int iv = (int)sv;
            pk[s][j >> 2] |= ((unsigned)iv & 0xffu) << ((j & 3) * 8);
        }
    }
#pragma unroll
    for (int s = 0; s < 5; ++s) {
        char* dst = xs + (size_t)(((s * 256 + t0) * 32 + kt) * 2 + mt) * 1024
                       + lane * 16;
        *(uint4*)dst = make_uint4(pk[s][0], pk[s][1], pk[s][2], pk[s][3]);
    }
}

// -----------------------------------------------------------------------------
// Split W into 5 i8 slices, fixed scale 2^-2, B-frag chunk order:
// chunk(s,ot,kt) = 1KB, element = W[o=ot*32+n][kt*32+kh*16+j].
// -----------------------------------------------------------------------------
__global__ __launch_bounds__(256) void snn_split_w(
    const float* __restrict__ Wt, char* __restrict__ wsl)
{
    const int W    = blockIdx.x * 4 + (threadIdx.x >> 6);   // 0..1023
    const int lane = threadIdx.x & 63;
    const int kt = W & 31, ot = W >> 5;
    const int n = lane & 31, kh = lane >> 5;
    const int o = ot * 32 + n;

    const float* src = Wt + (size_t)o * DIN_ + kt * 32 + kh * 16;
    float f[16];
    *(float4*)(f)      = *(const float4*)(src);
    *(float4*)(f + 4)  = *(const float4*)(src + 4);
    *(float4*)(f + 8)  = *(const float4*)(src + 8);
    *(float4*)(f + 12) = *(const float4*)(src + 12);

    unsigned pk[5][4];
#pragma unroll
    for (int s = 0; s < 5; ++s)
        pk[s][0] = pk[s][1] = pk[s][2] = pk[s][3] = 0u;
#pragma unroll
    for (int j = 0; j < 16; ++j) {
        float v = f[j] * 4.0f;                   // / 2^-2 (exact)
#pragma unroll
        for (int s = 0; s < 5; ++s) {
            const float ml = (s == 0) ? 64.f : 128.f;
            const float sv = __builtin_rintf(v * ml);
            v = v * ml - sv;
            const int iv = (int)sv;
            pk[s][j >> 2] |= ((unsigned)iv & 0xffu) << ((j & 3) * 8);
        }
    }
#pragma unroll
    for (int s = 0; s < 5; ++s) {
        char* dst = wsl + (size_t)((s * 32 + ot) * 32 + kt) * 1024 + lane * 16;
        *(uint4*)dst = make_uint4(pk[s][0], pk[s][1], pk[s][2], pk[s][3]);
    }
}

// -----------------------------------------------------------------------------
// GEMM via i8 MFMA. Tile 64b x 128o (grid 2048 = 256 t0 x 8 oB). Each wave:
// A tile wm = ws>>1, ot pair wop = (ws&1)*2 -> 30 MFMAs/kt (1100 cyc busy
// per barrier > ~900 cyc HBM drain: latency hides under compute).
// blockIdx = t0*8 + oB: with round-robin XCD assignment, oB pins to one XCD
// -> its 640 KB B-slice stays L2-resident; A (80 MB < L3) fetched once.
// DMA staging: waves 0,1 -> A (5 chunks), waves 2,3 -> B (10 chunks).
// 5 slices, 15 exact pair-MFMAs per ot into i32 accs -> bit-exact.
// -----------------------------------------------------------------------------
__global__ __launch_bounds__(256, 2) void snn_gemm_i8(
    const char* __restrict__ xs, const char* __restrict__ wsl,
    const float* __restrict__ bias, double* __restrict__ pre)
{
    __shared__ __align__(16) char lds[2][30 * 1024];   // A 10 + B 20 chunks
    const int t0 = blockIdx.x >> 3;
    const int oB = blockIdx.x & 7;           // == XCD id under %8 round-robin
    const int tid = threadIdx.x;
    const int lane = tid & 63;
    const int ws = __builtin_amdgcn_readfirstlane(tid >> 6);   // scalar wave id
    const int wm  = ws >> 1;                 // A tile this wave computes
    const int wop = (ws & 1) * 2;            // ot pair base (0 or 2)

    v16i zero;
#pragma unroll
    for (int r = 0; r < 16; ++r) zero[r] = 0;
    v16i acc[2][5];
#pragma unroll
    for (int p = 0; p < 2; ++p)
#pragma unroll
        for (int g = 0; g < 5; ++g) acc[p][g] = zero;

    const int lo = lane * 16;

    // DMA source bases (wave-uniform SGPRs)
    const char* agbase = xs + ((size_t)t0 * 32 * 2 + ws) * 1024;        // ws<2
    const char* bgbase = wsl + (size_t)(oB * 4 + (ws - 2) * 2) * 32 * 1024;

    // preload kt=0 into buffer 0
    if (ws < 2) {
#pragma unroll
        for (int s = 0; s < 5; ++s)
            async_copy16(agbase + (size_t)s * 16777216 + lo,
                         &lds[0][(ws * 5 + s) * 1024]);
    } else {
#pragma unroll
        for (int o2 = 0; o2 < 2; ++o2)
#pragma unroll
            for (int s = 0; s < 5; ++s)
                async_copy16(bgbase + (size_t)o2 * 32768 + (size_t)s * 1048576 + lo,
                             &lds[0][(10 + ((ws - 2) * 2 + o2) * 5 + s) * 1024]);
    }

    for (int kt = 0; kt < 32; ++kt) {
        __syncthreads();   // vmcnt(0) drain + cross-wave visibility
        if (kt + 1 < 32) { // stage kt+1 into the other buffer
            char* buf = lds[(kt + 1) & 1];
            if (ws < 2) {
                const char* g = agbase + (size_t)(kt + 1) * 2048;
#pragma unroll
                for (int s = 0; s < 5; ++s)
                    async_copy16(g + (size_t)s * 16777216 + lo,
                                 &buf[(ws * 5 + s) * 1024]);
            } else {
                const char* g = bgbase + (size_t)(kt + 1) * 1024;
#pragma unroll
                for (int o2 = 0; o2 < 2; ++o2)
#pragma unroll
                    for (int s = 0; s < 5; ++s)
                        async_copy16(g + (size_t)o2 * 32768 + (size_t)s * 1048576 + lo,
                                     &buf[(10 + ((ws - 2) * 2 + o2) * 5 + s) * 1024]);
            }
        }
        const char* cbuf = lds[kt & 1];
        v4i a[5];
#pragma unroll
        for (int s = 0; s < 5; ++s)
            a[s] = *(const v4i*)(cbuf + (wm * 5 + s) * 1024 + lo);
#pragma unroll
        for (int o2 = 0; o2 < 2; ++o2) {
            v4i b[5];
#pragma unroll
            for (int s = 0; s < 5; ++s)
                b[s] = *(const v4i*)(cbuf + (10 + (wop + o2) * 5 + s) * 1024 + lo);
#pragma unroll
            for (int i = 0; i < 5; ++i) {
#pragma unroll
                for (int j = 0; j < 5 - i; ++j)
                    acc[o2][i + j] = __builtin_amdgcn_mfma_i32_32x32x32_i8(
                        a[i], b[j], acc[o2][i + j], 0, 0, 0);
            }
        }
    }

    // epilogue: D layout col=lane&31 (o), row=(r&3)+8*(r>>2)+4*(lane>>5) (b)
    const int n = lane & 31, lh = lane >> 5;
#pragma unroll
    for (int o2 = 0; o2 < 2; ++o2) {
        const int o = oB * 128 + (wop + o2) * 32 + n;
        const double bv = (double)bias[o];
        double* dst = pre + ((size_t)t0 * DOUT_ + o) * 64 + wm * 32;
#pragma unroll
        for (int r = 0; r < 16; ++r) {
            const int row = (r & 3) + 8 * (r >> 2) + 4 * lh;
            double v = (double)acc[o2][4][r];
            v = v * 0.0078125 + (double)acc[o2][3][r];
            v = v * 0.0078125 + (double)acc[o2][2][r];
            v = v * 0.0078125 + (double)acc[o2][1][r];
            v = v * 0.0078125 + (double)acc[o2][0][r];
            dst[row] = v * 0x1p-11 + bv;         // 2^{3-2-12}
        }
    }
}

// -----------------------------------------------------------------------------
// Fallback GEMM (round-8 proven fp64-VALU path), used when ws is small.
// -----------------------------------------------------------------------------
__global__ __launch_bounds__(256, 2) void snn_gemm_fb(
    const float* __restrict__ x, const float* __restrict__ W,
    const float* __restrict__ bias, double* __restrict__ pre)
{
    __shared__ float smem[2][8 * 72 + 8 * 256];
    const int t0 = blockIdx.x & 255;
    const int o0 = blockIdx.x >> 8;
    const int tid = threadIdx.x;
    const int to = tid & 31;
    const int tb = tid >> 5;

    double acc[8][8];
#pragma unroll
    for (int i = 0; i < 8; ++i)
#pragma unroll
        for (int j = 0; j < 8; ++j) acc[i][j] = 0.0;

    const int arow = tid >> 2;
    const int ak2  = (tid & 3) * 2;
    const float* xg = x + (size_t)(t0 + 256 * arow) * DIN_ + ak2;
    const float* wg = W + (size_t)(o0 * 256 + tid) * DIN_;

    float2 f2  = *(const float2*)(xg);
    float4 bq0 = *(const float4*)(wg);
    float4 bq1 = *(const float4*)(wg + 4);

    for (int kc = 0; kc < DIN_ / 8; ++kc) {
        float* base = smem[kc & 1];
        float (*AsF)[72]  = (float(*)[72])base;
        float (*BsF)[256] = (float(*)[256])(base + 8 * 72);
        AsF[ak2 + 0][arow] = f2.x;
        AsF[ak2 + 1][arow] = f2.y;
        BsF[0][tid] = bq0.x;  BsF[1][tid] = bq0.y;
        BsF[2][tid] = bq0.z;  BsF[3][tid] = bq0.w;
        BsF[4][tid] = bq1.x;  BsF[5][tid] = bq1.y;
        BsF[6][tid] = bq1.z;  BsF[7][tid] = bq1.w;
        __syncthreads();
        if (kc + 1 < DIN_ / 8) {
            f2  = *(const float2*)(xg + (kc + 1) * 8);
            bq0 = *(const float4*)(wg + (kc + 1) * 8);
            bq1 = *(const float4*)(wg + (kc + 1) * 8 + 4);
        }
#pragma unroll
        for (int k = 0; k < 8; ++k) {
            const float4 af0 = *(const float4*)&AsF[k][tb * 8];
            const float4 af1 = *(const float4*)&AsF[k][tb * 8 + 4];
            const float4 bf0 = *(const float4*)&BsF[k][to * 4];
            const float4 bf1 = *(const float4*)&BsF[k][128 + to * 4];
            double a[8], b[8];
            a[0] = (double)af0.x; a[1] = (double)af0.y;
            a[2] = (double)af0.z; a[3] = (double)af0.w;
            a[4] = (double)af1.x; a[5] = (double)af1.y;
            a[6] = (double)af1.z; a[7] = (double)af1.w;
            b[0] = (double)bf0.x; b[1] = (double)bf0.y;
            b[2] = (double)bf0.z; b[3] = (double)bf0.w;
            b[4] = (double)bf1.x; b[5] = (double)bf1.y;
            b[6] = (double)bf1.z; b[7] = (double)bf1.w;
#pragma unroll
            for (int i = 0; i < 8; ++i)
#pragma unroll
                for (int j = 0; j < 8; ++j)
                    acc[i][j] += a[i] * b[j];
        }
    }

    double biasd[8];
#pragma unroll
    for (int j = 0; j < 8; ++j)
        biasd[j] = (double)bias[o0 * 256 + (j >> 2) * 128 + to * 4 + (j & 3)];
    double (*trans)[67] = (double(*)[67])smem[0];
    for (int c = 0; c < 16; ++c) {
        __syncthreads();
        const int j4  = c >> 3;
        const int tlo = (c & 7) * 4;
        if (to >= tlo && to < tlo + 4) {
#pragma unroll
            for (int p4 = 0; p4 < 4; ++p4) {
                const int r = (to - tlo) * 4 + p4;
                const int j = j4 * 4 + p4;
#pragma unroll
                for (int i = 0; i < 8; ++i)
                    trans[r][tb * 8 + i] = acc[i][j] + biasd[j];
            }
        }
        __syncthreads();
#pragma unroll
        for (int q = 0; q < 4; ++q) {
            const int idx = tid + 256 * q;
            const int b  = idx & 63;
            const int oc = idx >> 6;
            pre[(size_t)(t0 * DOUT_ + o0 * 256 + c * 16 + oc) * 64 + b] = trans[oc][b];
        }
    }
}

// -----------------------------------------------------------------------------
// Scan: one wave per o, lane = b. Batch-mean via ballot+popcount.
// 16-deep load grouping (~8 MB in flight across 1024 waves) for HBM overlap.
// -----------------------------------------------------------------------------
__global__ __launch_bounds__(256) void snn_scan(
    const double* __restrict__ pre, const float* __restrict__ thr_in,
    unsigned long long* __restrict__ spM, float* __restrict__ outD)
{
    const int wid  = (blockIdx.x * blockDim.x + threadIdx.x) >> 6;
    const int lane = threadIdx.x & 63;
    if (wid >= DOUT_) return;
    const int o = wid;

    double mem = 0.0;
    double thr = (double)thr_in[o];
    const double* p = pre + (size_t)o * 64 + lane;

    for (int t = 0; t < T_; t += 16) {
        double pv[16];
#pragma unroll
        for (int j = 0; j < 16; ++j)
            pv[j] = p[(size_t)(t + j) * (DOUT_ * 64)];
#pragma unroll
        for (int j = 0; j < 16; ++j) {
            mem += pv[j];
            const bool s = (mem >= thr);
            const unsigned long long msk = __ballot(s);
            const int cnt = __popcll(msk);
            thr += 0.05 * ((double)cnt * (1.0 / 64.0) - 0.5);
            if (spM) {
                if (lane == 0) spM[(size_t)(t + j) * DOUT_ + o] = msk;
            } else {
                outD[(size_t)lane * (T_ * DOUT_) + (size_t)(t + j) * DOUT_ + o] =
                    s ? 1.0f : 0.0f;
            }
            mem = s ? 0.0 : mem;
        }
    }
}

__global__ __launch_bounds__(256) void snn_expand(
    const unsigned long long* __restrict__ spM, float* __restrict__ out)
{
    const int r = blockIdx.x * 256 + threadIdx.x;
    const unsigned long long m = spM[r];
#pragma unroll
    for (int b = 0; b < 64; ++b)
        out[(size_t)b * (T_ * DOUT_) + r] = (float)((m >> b) & 1ULL);
}

extern "C" void kernel_launch(void* const* d_in, const int* in_sizes, int n_in,
                              void* d_out, int out_size, void* d_ws, size_t ws_size,
                              hipStream_t stream) {
    const float* x    = (const float*)d_in[0];   // [64][256][1024]
    const float* W    = (const float*)d_in[1];   // [1024][1024]
    const float* bias = (const float*)d_in[2];   // [1024]
    const float* thr  = (const float*)d_in[3];   // [1024]
    float* out = (float*)d_out;                  // [64][256][1024]

    double* pre = (double*)d_ws;
    const size_t need = PRE_BYTES + XS_BYTES + WSL_BYTES + SPM_BYTES;

    if (ws_size >= need) {
        char* xs  = (char*)d_ws + PRE_BYTES;
        char* wsl = xs + XS_BYTES;
        unsigned long long* spM = (unsigned long long*)(wsl + WSL_BYTES);
        snn_split_x<<<4096, 256, 0, stream>>>(x, xs);
        snn_split_w<<<256, 256, 0, stream>>>(W, wsl);
        snn_gemm_i8<<<2048, 256, 0, stream>>>(xs, wsl, bias, pre);
        snn_scan<<<256, 256, 0, stream>>>(pre, thr, spM, nullptr);
        snn_expand<<<1024, 256, 0, stream>>>(spM, out);
    } else {
        const bool two_stage = (ws_size >= PRE_BYTES + SPM_BYTES);
        unsigned long long* spM =
            two_stage ? (unsigned long long*)((char*)d_ws + PRE_BYTES) : nullptr;
        snn_gemm_fb<<<1024, 256, 0, stream>>>(x, W, bias, pre);
        snn_scan<<<256, 256, 0, stream>>>(pre, thr, spM, two_stage ? nullptr : out);
        if (two_stage)
            snn_expand<<<1024, 256, 0, stream>>>(spM, out);
    }
}